// Round 9
// baseline (149.076 us; speedup 1.0000x reference)
//
#include <hip/hip_runtime.h>
#include <hip/hip_bf16.h>
#include <cstdint>
#include <cstddef>

#define T_SEQ 2048
#define NH    16
#define HD    64
#define EMB   1024
#define BATCH 4
#define NT    (T_SEQ / 64)

typedef unsigned short u16;
typedef unsigned int   u32;
typedef u16   u16x8  __attribute__((ext_vector_type(8)));
typedef short bf16x8 __attribute__((ext_vector_type(8)));
typedef float f32x4  __attribute__((ext_vector_type(4)));
typedef u32   u32x4  __attribute__((ext_vector_type(4)));

typedef const __attribute__((address_space(1))) void* gptr_t;
typedef __attribute__((address_space(3))) void*       lptr_t;

__device__ __forceinline__ u16 f2bf(float f) {
    union { float f; unsigned u; } v; v.f = f;
    unsigned r = v.u + 0x7fffu + ((v.u >> 16) & 1u);
    return (u16)(r >> 16);
}

__device__ __forceinline__ u32 cvtpk(float lo, float hi) {
    u32 r;
    asm("v_cvt_pk_bf16_f32 %0, %1, %2" : "=v"(r) : "v"(lo), "v"(hi));
    return r;
}

// storage row R -> source kv row, so that S^T C-layout == PV fragment layout.
__device__ __forceinline__ int invpi(int R) {
    return ((R >> 5) << 5) | (((R >> 2) & 3) << 3) | (((R >> 4) & 1) << 2) | (R & 3);
}

// ---------------- kernel 0: fused weight converts ----------------
__global__ __launch_bounds__(256) void msa_convert(
    const float* __restrict__ wproj, const float* __restrict__ wqkv,
    u16* __restrict__ wb, u16* __restrict__ wimg)
{
    const int bid = blockIdx.x, tid = threadIdx.x;
    if (bid < 1024) {
        int i = (bid * 256 + tid) * 4;
        f32x4 f = *(const f32x4*)(wproj + i);
        u16 o0 = f2bf(f[0]), o1 = f2bf(f[1]), o2 = f2bf(f[2]), o3 = f2bf(f[3]);
        wb[i + 0] = o0; wb[i + 1] = o1; wb[i + 2] = o2; wb[i + 3] = o3;
    } else {
        const int gid = (bid - 1024) * 256 + tid;   // 0..1535
        if (gid < 1536) {
            const int r = gid >> 3, c8 = gid & 7;
            const float* src = wqkv + r * 64 + c8 * 8;
            f32x4 f0 = *(const f32x4*)src, f1 = *(const f32x4*)(src + 4);
            u32x4 pk = { cvtpk(f0[0], f0[1]), cvtpk(f0[2], f0[3]),
                         cvtpk(f1[0], f1[1]), cvtpk(f1[2], f1[3]) };
            *(u32x4*)&wimg[r * 64 + ((c8 ^ (r & 7)) << 3)] = pk;
        }
    }
}

// ---------------- kernel 1: QKV projection (bf16 MFMA) ----------------
__global__ __launch_bounds__(256) void msa_qkv(
    const float* __restrict__ x, const u16* __restrict__ wimg,
    const float* __restrict__ bqkv,
    u16* __restrict__ qg, u16* __restrict__ kg, u16* __restrict__ vt)
{
    __shared__ __align__(16) u16 sm[16384];   // 32 KB
    u16* Xs = sm;                              // [64][64] swizzled
    u16* Wl = sm + 4096;                       // [192][64] swizzled image

    const int tid = threadIdx.x, l = tid & 63, w = tid >> 6;
    const int lr = l & 15, lg = l >> 4;
    const int bh = blockIdx.y, b = bh >> 4, h = bh & 15;
    const int t0 = blockIdx.x * 64;

    #pragma unroll
    for (int j = 0; j < 6; j++)
        __builtin_amdgcn_global_load_lds((gptr_t)(wimg + j * 2048 + w * 512 + l * 8),
                                         (lptr_t)(Wl + j * 2048 + w * 512), 16, 0, 0);

    #pragma unroll
    for (int g = 0; g < 2; g++) {
        const int chunk = g * 256 + tid;
        const int row = chunk >> 3, c8 = chunk & 7;
        const float* src = x + ((size_t)(b * T_SEQ + t0 + row)) * EMB + h * HD + c8 * 8;
        f32x4 f0 = *(const f32x4*)src, f1 = *(const f32x4*)(src + 4);
        u32x4 pk = { cvtpk(f0[0], f0[1]), cvtpk(f0[2], f0[3]),
                     cvtpk(f1[0], f1[1]), cvtpk(f1[2], f1[3]) };
        *(u32x4*)&Xs[row * 64 + ((c8 ^ (row & 7)) << 3)] = pk;
    }

    float bv[12];
    #pragma unroll
    for (int dt = 0; dt < 12; dt++) bv[dt] = bqkv[dt * 16 + lr];

    __syncthreads();

    const int xr = w * 16 + lr;
    bf16x8 af[2];
    #pragma unroll
    for (int kk = 0; kk < 2; kk++)
        af[kk] = *(const bf16x8*)&Xs[xr * 64 + ((((kk << 2) | lg) ^ (xr & 7)) << 3)];

    f32x4 acc[12];
    #pragma unroll
    for (int dt = 0; dt < 12; dt++) acc[dt] = (f32x4){0.f, 0.f, 0.f, 0.f};
    #pragma unroll
    for (int dt = 0; dt < 12; dt++) {
        const int wr = dt * 16 + lr;
        #pragma unroll
        for (int kk = 0; kk < 2; kk++) {
            bf16x8 wf = *(const bf16x8*)&Wl[wr * 64 + ((((kk << 2) | lg) ^ (wr & 7)) << 3)];
            acc[dt] = __builtin_amdgcn_mfma_f32_16x16x32_bf16(af[kk], wf, acc[dt], 0, 0, 0);
        }
    }

    const float qscale = 0.125f * 1.44269504088896340736f;
    #pragma unroll
    for (int dt = 0; dt < 12; dt++)
        #pragma unroll
        for (int i = 0; i < 4; i++) {
            acc[dt][i] += bv[dt];
            if (dt < 4) acc[dt][i] *= qscale;
        }

    // V: direct 8B stores
    #pragma unroll
    for (int dt = 8; dt < 12; dt++) {
        const int d = (dt - 8) * 16 + lr;
        const int t = t0 + w * 16 + lg * 4;
        u32 w0 = cvtpk(acc[dt][0], acc[dt][1]);
        u32 w1 = cvtpk(acc[dt][2], acc[dt][3]);
        u32* dst = (u32*)&vt[((size_t)bh * HD + d) * T_SEQ + t];
        dst[0] = w0; dst[1] = w1;
    }

    // Q,K via per-wave LDS transpose then coalesced stores
    __syncthreads();
    u16* qep = sm + w * 1024;
    u16* kep = sm + 4096 + w * 1024;
    #pragma unroll
    for (int dt = 0; dt < 8; dt++) {
        u16* ep = dt < 4 ? qep : kep;
        const int d = (dt & 3) * 16 + lr;
        const int c8 = d >> 3;
        #pragma unroll
        for (int i = 0; i < 4; i++) {
            const int r = lg * 4 + i;
            ep[r * 64 + ((c8 ^ (r & 7)) << 3) + (d & 7)] = (u16)cvtpk(acc[dt][i], acc[dt][i]);
        }
    }
    __syncthreads();
    #pragma unroll
    for (int j = 0; j < 2; j++) {
        const int row = l >> 2, c8 = (l & 3) * 2 + j;
        const size_t grow = ((size_t)bh * T_SEQ + t0 + w * 16 + row) * HD + c8 * 8;
        u16x8 vq = *(const u16x8*)&qep[row * 64 + ((c8 ^ (row & 7)) << 3)];
        *(u16x8*)&qg[grow] = vq;
        u16x8 vk = *(const u16x8*)&kep[row * 64 + ((c8 ^ (row & 7)) << 3)];
        *(u16x8*)&kg[grow] = vk;
    }
}

// ---------------- kernel 2: flash attention (no-max exp2, kk-interleaved TILE) ----
__global__ __launch_bounds__(256, 4) void msa_attn(
    const u16* __restrict__ qg, const u16* __restrict__ kg,
    const u16* __restrict__ vtg, u16* __restrict__ att)
{
    __shared__ u16 lds_k[2][4096];
    __shared__ u16 lds_v[2][4096];

    const int tid = threadIdx.x, l = tid & 63, w = tid >> 6;
    const int lr = l & 15, lg = l >> 4;

    const int lin = blockIdx.y * 16 + blockIdx.x;
    const int xcd = lin & 7, seq = lin >> 3;
    const int bh  = xcd * 8 + (seq & 7);
    const int q0  = (seq >> 3) * 128;
    const int b = bh >> 4, h = bh & 15;

    const u16* qp  = qg  + (size_t)bh * T_SEQ * HD;
    const u16* kp  = kg  + (size_t)bh * T_SEQ * HD;
    const u16* vtp = vtg + (size_t)bh * HD * T_SEQ;

    const int R0 = w * 16 + (l >> 3), R1 = R0 + 8, c8p = l & 7;
    const int sw0 = (c8p ^ (R0 & 7)) << 3, sw1 = (c8p ^ (R1 & 7)) << 3;
    const size_t koff0 = (size_t)invpi(R0) * HD + sw0;
    const size_t koff1 = (size_t)invpi(R1) * HD + sw1;
    const size_t voff0 = (size_t)R0 * T_SEQ + sw0;
    const size_t voff1 = (size_t)R1 * T_SEQ + sw1;

#define STAGE(bufi, kvb) do {                                                              \
    __builtin_amdgcn_global_load_lds((gptr_t)(kp + (size_t)(kvb) * HD + koff0),            \
                                     (lptr_t)&lds_k[bufi][w * 1024],       16, 0, 0);      \
    __builtin_amdgcn_global_load_lds((gptr_t)(kp + (size_t)(kvb) * HD + koff1),            \
                                     (lptr_t)&lds_k[bufi][w * 1024 + 512], 16, 0, 0);      \
    __builtin_amdgcn_global_load_lds((gptr_t)(vtp + (size_t)(kvb) + voff0),                \
                                     (lptr_t)&lds_v[bufi][w * 1024],       16, 0, 0);      \
    __builtin_amdgcn_global_load_lds((gptr_t)(vtp + (size_t)(kvb) + voff1),                \
                                     (lptr_t)&lds_v[bufi][w * 1024 + 512], 16, 0, 0);      \
} while (0)

    STAGE(0, 0);
    __builtin_amdgcn_sched_barrier(0);

    bf16x8 qf[2][2];
    #pragma unroll
    for (int qt = 0; qt < 2; qt++)
        #pragma unroll
        for (int kk = 0; kk < 2; kk++)
            qf[qt][kk] = *(const bf16x8*)(qp +
                (size_t)(q0 + w * 32 + qt * 16 + lr) * HD + (kk * 4 + lg) * 8);

    f32x4 o[2][4];
    #pragma unroll
    for (int qt = 0; qt < 2; qt++)
        #pragma unroll
        for (int dt = 0; dt < 4; dt++) o[qt][dt] = (f32x4){0.f, 0.f, 0.f, 0.f};
    f32x4 l_acc[2] = {(f32x4){0.f, 0.f, 0.f, 0.f}, (f32x4){0.f, 0.f, 0.f, 0.f}};

    const u32x4 onesw = {0x3f803f80u, 0x3f803f80u, 0x3f803f80u, 0x3f803f80u};
    const bf16x8 onesf = *(const bf16x8*)&onesw;

    f32x4 s0[4], s1[4];

#define COMPUTE_S(bufi) do {                                                               \
    const u16* ksb_ = &lds_k[bufi][0];                                                     \
    __builtin_amdgcn_s_setprio(1);                                                         \
    _Pragma("unroll")                                                                      \
    for (int kk = 0; kk < 2; kk++) {                                                       \
        bf16x8 kf[4];                                                                      \
        _Pragma("unroll")                                                                  \
        for (int m = 0; m < 4; m++)                                                        \
            kf[m] = *(const bf16x8*)&ksb_[m * 1024 + lr * 64 +                             \
                                          ((((kk << 2) | lg) ^ (lr & 7)) << 3)];           \
        if (kk == 0) {                                                                     \
            _Pragma("unroll")                                                              \
            for (int m = 0; m < 4; m++) {                                                  \
                s0[m] = __builtin_amdgcn_mfma_f32_16x16x32_bf16(                           \
                    kf[m], qf[0][0], (f32x4){0.f, 0.f, 0.f, 0.f}, 0, 0, 0);                \
                s1[m] = __builtin_amdgcn_mfma_f32_16x16x32_bf16(                           \
                    kf[m], qf[1][0], (f32x4){0.f, 0.f, 0.f, 0.f}, 0, 0, 0);                \
            }                                                                              \
        } else {                                                                           \
            _Pragma("unroll")                                                              \
            for (int m = 0; m < 4; m++) {                                                  \
                s0[m] = __builtin_amdgcn_mfma_f32_16x16x32_bf16(kf[m], qf[0][1], s0[m], 0, 0, 0); \
                s1[m] = __builtin_amdgcn_mfma_f32_16x16x32_bf16(kf[m], qf[1][1], s1[m], 0, 0, 0); \
            }                                                                              \
        }                                                                                  \
    }                                                                                      \
    __builtin_amdgcn_s_setprio(0);                                                         \
} while (0)

// kk-interleaved: per kk-half {vf reads -> exp2 x16 -> pack x8 -> 10 MFMA}.
// kk=1's exp2 burst overlaps kk=0's MFMA drain in the matrix pipe (in-order issue,
// but MFMA issue is short); vf ds_read latency hides under the same half's exp2.
#define TILE(bufi) do {                                                                    \
    COMPUTE_S(bufi);                                                                       \
    const u16* vsb_ = &lds_v[bufi][0];                                                     \
    _Pragma("unroll")                                                                      \
    for (int kk = 0; kk < 2; kk++) {                                                       \
        bf16x8 vfk[4];                                                                     \
        _Pragma("unroll")                                                                  \
        for (int dt = 0; dt < 4; dt++)                                                     \
            vfk[dt] = *(const bf16x8*)&vsb_[dt * 1024 + lr * 64 +                          \
                                            ((((kk << 2) | lg) ^ (lr & 7)) << 3)];         \
        _Pragma("unroll")                                                                  \
        for (int m = 2 * kk; m < 2 * kk + 2; m++)                                          \
            _Pragma("unroll")                                                              \
            for (int i = 0; i < 4; i++) {                                                  \
                s0[m][i] = exp2f(s0[m][i]);                                                \
                s1[m][i] = exp2f(s1[m][i]);                                                \
            }                                                                              \
        u32 pw0[4], pw1[4];                                                                \
        _Pragma("unroll")                                                                  \
        for (int wd = 0; wd < 4; wd++) {                                                   \
            pw0[wd] = cvtpk(s0[2 * kk + (wd >> 1)][2 * (wd & 1)],                          \
                            s0[2 * kk + (wd >> 1)][2 * (wd & 1) + 1]);                     \
            pw1[wd] = cvtpk(s1[2 * kk + (wd >> 1)][2 * (wd & 1)],                          \
                            s1[2 * kk + (wd >> 1)][2 * (wd & 1) + 1]);                     \
        }                                                                                  \
        u32x4 p0w = {pw0[0], pw0[1], pw0[2], pw0[3]};                                      \
        u32x4 p1w = {pw1[0], pw1[1], pw1[2], pw1[3]};                                      \
        bf16x8 pf0 = *(bf16x8*)&p0w, pf1 = *(bf16x8*)&p1w;                                 \
        __builtin_amdgcn_s_setprio(1);                                                     \
        l_acc[0] = __builtin_amdgcn_mfma_f32_16x16x32_bf16(onesf, pf0, l_acc[0], 0, 0, 0); \
        l_acc[1] = __builtin_amdgcn_mfma_f32_16x16x32_bf16(onesf, pf1, l_acc[1], 0, 0, 0); \
        _Pragma("unroll")                                                                  \
        for (int dt = 0; dt < 4; dt++) {                                                   \
            o[0][dt] = __builtin_amdgcn_mfma_f32_16x16x32_bf16(vfk[dt], pf0, o[0][dt], 0, 0, 0); \
            o[1][dt] = __builtin_amdgcn_mfma_f32_16x16x32_bf16(vfk[dt], pf1, o[1][dt], 0, 0, 0); \
        }                                                                                  \
        __builtin_amdgcn_s_setprio(0);                                                     \
    }                                                                                      \
} while (0)

    for (int tt = 0; tt < NT; tt += 2) {
        // ---- tile tt in buf 0 ----
        __builtin_amdgcn_s_barrier();
        {
            STAGE(1, (tt + 1) * 64);           // tt+1 < NT always (NT even)
            __builtin_amdgcn_sched_barrier(0);
            asm volatile("s_waitcnt vmcnt(4)" ::: "memory");
        }
        __builtin_amdgcn_sched_barrier(0);
        __builtin_amdgcn_s_barrier();
        __builtin_amdgcn_sched_barrier(0);
        TILE(0);

        // ---- tile tt+1 in buf 1 ----
        __builtin_amdgcn_s_barrier();
        if (tt + 2 < NT) {
            STAGE(0, (tt + 2) * 64);
            __builtin_amdgcn_sched_barrier(0);
            asm volatile("s_waitcnt vmcnt(4)" ::: "memory");
        } else {
            asm volatile("s_waitcnt vmcnt(0)" ::: "memory");
        }
        __builtin_amdgcn_sched_barrier(0);
        __builtin_amdgcn_s_barrier();
        __builtin_amdgcn_sched_barrier(0);
        TILE(1);
    }
#undef STAGE
#undef COMPUTE_S
#undef TILE

    // epilogue: O^T[d][q] -> att[t][d] via per-wave LDS transpose
    __syncthreads();
    u16* ep = &lds_k[0][0] + w * 2048;
    #pragma unroll
    for (int qt = 0; qt < 2; qt++) {
        const float iv = 1.0f / l_acc[qt][0];
        #pragma unroll
        for (int dt = 0; dt < 4; dt++) {
            u32 a  = cvtpk(o[qt][dt][0] * iv, o[qt][dt][1] * iv);
            u32 bb = cvtpk(o[qt][dt][2] * iv, o[qt][dt][3] * iv);
            const int row = qt * 16 + lr;
            const int c8 = dt * 2 + (lg >> 1);
            u32* dst = (u32*)&ep[row * 64 + ((c8 ^ (row & 7)) << 3) + (lg & 1) * 4];
            dst[0] = a; dst[1] = bb;
        }
    }
    __syncthreads();
    {
        const int row = l >> 1;
        const int tq = q0 + w * 32 + row;
        u16* gdst = att + ((size_t)b * T_SEQ + tq) * EMB + h * HD;
        #pragma unroll
        for (int ci = 0; ci < 4; ci++) {
            const int c = (l & 1) * 4 + ci;
            u16x8 v = *(const u16x8*)&ep[row * 64 + ((c ^ (row & 7)) << 3)];
            *(u16x8*)&gdst[c * 8] = v;
        }
    }
}

// ---------------- kernel 3: output projection (counted vmcnt, XCD-local tiles) -----
__global__ __launch_bounds__(256) void msa_proj(
    const u16* __restrict__ a, const u16* __restrict__ wb,
    const float* __restrict__ bias, float* __restrict__ y)
{
    __shared__ u16 as[2][8192];
    __shared__ u16 bs[2][8192];

    const int tid = threadIdx.x, l = tid & 63, w = tid >> 6;

    // XCD-local mapping: XCD k owns m-tiles [8k,8k+8), n fastest.
    const int lin = blockIdx.y * 8 + blockIdx.x;   // 0..511
    const int xcd = lin & 7, s = lin >> 3;         // s 0..63
    const int m0 = (xcd * 8 + (s >> 3)) * 128;
    const int n0 = (s & 7) * 128;

    const int wr = (w >> 1) * 64, wc = (w & 1) * 64;
    const int lr = l & 15, lg = l >> 4;

    const int sr = l >> 3, c8 = l & 7;
    size_t aoff[4], boff[4];
    #pragma unroll
    for (int j = 0; j < 4; j++) {
        const int row = w * 32 + j * 8 + sr;
        const int col = (c8 ^ (row & 7)) << 3;
        aoff[j] = (size_t)(m0 + row) * EMB + col;
        boff[j] = (size_t)(n0 + row) * EMB + col;
    }

#define PSTAGE(bi, kk0) do {                                                               \
    _Pragma("unroll")                                                                      \
    for (int j = 0; j < 4; j++) {                                                          \
        __builtin_amdgcn_global_load_lds((gptr_t)(a + aoff[j] + (kk0)),                    \
            (lptr_t)&as[bi][(w * 32 + j * 8) * 64], 16, 0, 0);                             \
        __builtin_amdgcn_global_load_lds((gptr_t)(wb + boff[j] + (kk0)),                   \
            (lptr_t)&bs[bi][(w * 32 + j * 8) * 64], 16, 0, 0);                             \
    }                                                                                      \
} while (0)

#define PCOMPUTE(bi) do {                                                                  \
    bf16x8 af[4][2], bf[4][2];                                                             \
    _Pragma("unroll")                                                                      \
    for (int mt = 0; mt < 4; mt++)                                                         \
        _Pragma("unroll")                                                                  \
        for (int kk = 0; kk < 2; kk++) {                                                   \
            const int row = wr + mt * 16 + lr;                                             \
            const int cc = kk * 4 + lg;                                                    \
            af[mt][kk] = *(const bf16x8*)&as[bi][row * 64 + ((cc ^ (row & 7)) << 3)];      \
        }                                                                                  \
    _Pragma("unroll")                                                                      \
    for (int nt = 0; nt < 4; nt++)                                                         \
        _Pragma("unroll")                                                                  \
        for (int kk = 0; kk < 2; kk++) {                                                   \
            const int row = wc + nt * 16 + lr;                                             \
            const int cc = kk * 4 + lg;                                                    \
            bf[nt][kk] = *(const bf16x8*)&bs[bi][row * 64 + ((cc ^ (row & 7)) << 3)];      \
        }                                                                                  \
    __builtin_amdgcn_s_setprio(1);                                                         \
    _Pragma("unroll")                                                                      \
    for (int mt = 0; mt < 4; mt++)                                                         \
        _Pragma("unroll")                                                                  \
        for (int nt = 0; nt < 4; nt++)                                                     \
            _Pragma("unroll")                                                              \
            for (int kk = 0; kk < 2; kk++)                                                 \
                acc[mt][nt] = __builtin_amdgcn_mfma_f32_16x16x32_bf16(                     \
                    af[mt][kk], bf[nt][kk], acc[mt][nt], 0, 0, 0);                         \
    __builtin_amdgcn_s_setprio(0);                                                         \
} while (0)

    f32x4 acc[4][4];
    #pragma unroll
    for (int mt = 0; mt < 4; mt++)
        #pragma unroll
        for (int nt = 0; nt < 4; nt++) acc[mt][nt] = (f32x4){0.f, 0.f, 0.f, 0.f};

    PSTAGE(0, 0);

    for (int k0 = 0; k0 < EMB; k0 += 128) {
        // ---- K-step k0 in buf 0 ----
        __builtin_amdgcn_s_barrier();
        {
            PSTAGE(1, k0 + 64);
            __builtin_amdgcn_sched_barrier(0);
            asm volatile("s_waitcnt vmcnt(8)" ::: "memory");
        }
        __builtin_amdgcn_sched_barrier(0);
        __builtin_amdgcn_s_barrier();
        __builtin_amdgcn_sched_barrier(0);
        PCOMPUTE(0);

        // ---- K-step k0+64 in buf 1 ----
        __builtin_amdgcn_s_barrier();
        if (k0 + 128 < EMB) {
            PSTAGE(0, k0 + 128);
            __builtin_amdgcn_sched_barrier(0);
            asm volatile("s_waitcnt vmcnt(8)" ::: "memory");
        } else {
            asm volatile("s_waitcnt vmcnt(0)" ::: "memory");
        }
        __builtin_amdgcn_sched_barrier(0);
        __builtin_amdgcn_s_barrier();
        __builtin_amdgcn_sched_barrier(0);
        PCOMPUTE(1);
    }
#undef PSTAGE
#undef PCOMPUTE

    float bv[4];
    #pragma unroll
    for (int nt = 0; nt < 4; nt++) bv[nt] = bias[n0 + wc + nt * 16 + lr];
    #pragma unroll
    for (int mt = 0; mt < 4; mt++)
        #pragma unroll
        for (int nt = 0; nt < 4; nt++)
            #pragma unroll
            for (int i = 0; i < 4; i++) {
                const size_t row = (size_t)(m0 + wr + mt * 16 + lg * 4 + i);
                const int col = n0 + wc + nt * 16 + lr;
                y[row * EMB + col] = acc[mt][nt][i] + bv[nt];
            }
}

extern "C" void kernel_launch(void* const* d_in, const int* in_sizes, int n_in,
                              void* d_out, int out_size, void* d_ws, size_t ws_size,
                              hipStream_t stream)
{
    const float* x     = (const float*)d_in[0];
    const float* wqkv  = (const float*)d_in[1];
    const float* bqkv  = (const float*)d_in[2];
    const float* wproj = (const float*)d_in[3];
    const float* bproj = (const float*)d_in[4];
    float* y = (float*)d_out;

    char* ws = (char*)d_ws;
    u16* q    = (u16*)(ws);
    u16* k    = (u16*)(ws + ((size_t)16 << 20));
    u16* vt   = (u16*)(ws + ((size_t)32 << 20));
    u16* att  = (u16*)(ws + ((size_t)48 << 20));
    u16* wb   = (u16*)(ws + ((size_t)64 << 20));
    u16* wimg = (u16*)(ws + ((size_t)66 << 20));

    msa_convert<<<1030, 256, 0, stream>>>(wproj, wqkv, wb, wimg);
    msa_qkv<<<dim3(T_SEQ / 64, BATCH * NH), 256, 0, stream>>>(x, wimg, bqkv, q, k, vt);
    msa_attn<<<dim3(16, 64), 256, 0, stream>>>(q, k, vt, att);
    msa_proj<<<dim3(8, 64), 256, 0, stream>>>(att, wb, bproj, y);
}

// Round 10
// 114.411 us; speedup vs baseline: 1.3030x; 1.3030x over previous
//
#include <hip/hip_runtime.h>
#include <hip/hip_bf16.h>
#include <cstdint>
#include <cstddef>

#define T_SEQ 2048
#define NH    16
#define HD    64
#define EMB   1024
#define BATCH 4
#define NT    (T_SEQ / 64)

typedef unsigned short u16;
typedef unsigned int   u32;
typedef u16   u16x8  __attribute__((ext_vector_type(8)));
typedef short bf16x8 __attribute__((ext_vector_type(8)));
typedef float f32x4  __attribute__((ext_vector_type(4)));
typedef u32   u32x4  __attribute__((ext_vector_type(4)));

typedef const __attribute__((address_space(1))) void* gptr_t;
typedef __attribute__((address_space(3))) void*       lptr_t;

__device__ __forceinline__ u16 f2bf(float f) {
    union { float f; unsigned u; } v; v.f = f;
    unsigned r = v.u + 0x7fffu + ((v.u >> 16) & 1u);
    return (u16)(r >> 16);
}

__device__ __forceinline__ u32 cvtpk(float lo, float hi) {
    u32 r;
    asm("v_cvt_pk_bf16_f32 %0, %1, %2" : "=v"(r) : "v"(lo), "v"(hi));
    return r;
}

// raw v_exp_f32: 2^x, no OCML subnormal fixup (args bounded; FTZ result is
// exactly what softmax wants for very negative x).
__device__ __forceinline__ float fexp2(float x) {
    float r;
    asm("v_exp_f32 %0, %1" : "=v"(r) : "v"(x));
    return r;
}

// storage row R -> source kv row, so that S^T C-layout == PV fragment layout.
__device__ __forceinline__ int invpi(int R) {
    return ((R >> 5) << 5) | (((R >> 2) & 3) << 3) | (((R >> 4) & 1) << 2) | (R & 3);
}

// ---------------- kernel 0: fused weight converts ----------------
__global__ __launch_bounds__(256) void msa_convert(
    const float* __restrict__ wproj, const float* __restrict__ wqkv,
    u16* __restrict__ wb, u16* __restrict__ wimg)
{
    const int bid = blockIdx.x, tid = threadIdx.x;
    if (bid < 1024) {
        int i = (bid * 256 + tid) * 4;
        f32x4 f = *(const f32x4*)(wproj + i);
        u16 o0 = f2bf(f[0]), o1 = f2bf(f[1]), o2 = f2bf(f[2]), o3 = f2bf(f[3]);
        wb[i + 0] = o0; wb[i + 1] = o1; wb[i + 2] = o2; wb[i + 3] = o3;
    } else {
        const int gid = (bid - 1024) * 256 + tid;   // 0..1535
        if (gid < 1536) {
            const int r = gid >> 3, c8 = gid & 7;
            const float* src = wqkv + r * 64 + c8 * 8;
            f32x4 f0 = *(const f32x4*)src, f1 = *(const f32x4*)(src + 4);
            u32x4 pk = { cvtpk(f0[0], f0[1]), cvtpk(f0[2], f0[3]),
                         cvtpk(f1[0], f1[1]), cvtpk(f1[2], f1[3]) };
            *(u32x4*)&wimg[r * 64 + ((c8 ^ (r & 7)) << 3)] = pk;
        }
    }
}

// ---------------- kernel 1: QKV projection (bf16 MFMA) ----------------
__global__ __launch_bounds__(256) void msa_qkv(
    const float* __restrict__ x, const u16* __restrict__ wimg,
    const float* __restrict__ bqkv,
    u16* __restrict__ qg, u16* __restrict__ kg, u16* __restrict__ vt)
{
    __shared__ __align__(16) u16 sm[16384];   // 32 KB
    u16* Xs = sm;                              // [64][64] swizzled
    u16* Wl = sm + 4096;                       // [192][64] swizzled image

    const int tid = threadIdx.x, l = tid & 63, w = tid >> 6;
    const int lr = l & 15, lg = l >> 4;
    const int bh = blockIdx.y, b = bh >> 4, h = bh & 15;
    const int t0 = blockIdx.x * 64;

    #pragma unroll
    for (int j = 0; j < 6; j++)
        __builtin_amdgcn_global_load_lds((gptr_t)(wimg + j * 2048 + w * 512 + l * 8),
                                         (lptr_t)(Wl + j * 2048 + w * 512), 16, 0, 0);

    #pragma unroll
    for (int g = 0; g < 2; g++) {
        const int chunk = g * 256 + tid;
        const int row = chunk >> 3, c8 = chunk & 7;
        const float* src = x + ((size_t)(b * T_SEQ + t0 + row)) * EMB + h * HD + c8 * 8;
        f32x4 f0 = *(const f32x4*)src, f1 = *(const f32x4*)(src + 4);
        u32x4 pk = { cvtpk(f0[0], f0[1]), cvtpk(f0[2], f0[3]),
                     cvtpk(f1[0], f1[1]), cvtpk(f1[2], f1[3]) };
        *(u32x4*)&Xs[row * 64 + ((c8 ^ (row & 7)) << 3)] = pk;
    }

    float bv[12];
    #pragma unroll
    for (int dt = 0; dt < 12; dt++) bv[dt] = bqkv[dt * 16 + lr];

    __syncthreads();

    const int xr = w * 16 + lr;
    bf16x8 af[2];
    #pragma unroll
    for (int kk = 0; kk < 2; kk++)
        af[kk] = *(const bf16x8*)&Xs[xr * 64 + ((((kk << 2) | lg) ^ (xr & 7)) << 3)];

    f32x4 acc[12];
    #pragma unroll
    for (int dt = 0; dt < 12; dt++) acc[dt] = (f32x4){0.f, 0.f, 0.f, 0.f};
    #pragma unroll
    for (int dt = 0; dt < 12; dt++) {
        const int wr = dt * 16 + lr;
        #pragma unroll
        for (int kk = 0; kk < 2; kk++) {
            bf16x8 wf = *(const bf16x8*)&Wl[wr * 64 + ((((kk << 2) | lg) ^ (wr & 7)) << 3)];
            acc[dt] = __builtin_amdgcn_mfma_f32_16x16x32_bf16(af[kk], wf, acc[dt], 0, 0, 0);
        }
    }

    const float qscale = 0.125f * 1.44269504088896340736f;
    #pragma unroll
    for (int dt = 0; dt < 12; dt++)
        #pragma unroll
        for (int i = 0; i < 4; i++) {
            acc[dt][i] += bv[dt];
            if (dt < 4) acc[dt][i] *= qscale;
        }

    // V: direct 8B stores
    #pragma unroll
    for (int dt = 8; dt < 12; dt++) {
        const int d = (dt - 8) * 16 + lr;
        const int t = t0 + w * 16 + lg * 4;
        u32 w0 = cvtpk(acc[dt][0], acc[dt][1]);
        u32 w1 = cvtpk(acc[dt][2], acc[dt][3]);
        u32* dst = (u32*)&vt[((size_t)bh * HD + d) * T_SEQ + t];
        dst[0] = w0; dst[1] = w1;
    }

    // Q,K via per-wave LDS transpose then coalesced stores
    __syncthreads();
    u16* qep = sm + w * 1024;
    u16* kep = sm + 4096 + w * 1024;
    #pragma unroll
    for (int dt = 0; dt < 8; dt++) {
        u16* ep = dt < 4 ? qep : kep;
        const int d = (dt & 3) * 16 + lr;
        const int c8 = d >> 3;
        #pragma unroll
        for (int i = 0; i < 4; i++) {
            const int r = lg * 4 + i;
            ep[r * 64 + ((c8 ^ (r & 7)) << 3) + (d & 7)] = (u16)cvtpk(acc[dt][i], acc[dt][i]);
        }
    }
    __syncthreads();
    #pragma unroll
    for (int j = 0; j < 2; j++) {
        const int row = l >> 2, c8 = (l & 3) * 2 + j;
        const size_t grow = ((size_t)bh * T_SEQ + t0 + w * 16 + row) * HD + c8 * 8;
        u16x8 vq = *(const u16x8*)&qep[row * 64 + ((c8 ^ (row & 7)) << 3)];
        *(u16x8*)&qg[grow] = vq;
        u16x8 vk = *(const u16x8*)&kep[row * 64 + ((c8 ^ (row & 7)) << 3)];
        *(u16x8*)&kg[grow] = vk;
    }
}

// ---------------- kernel 2: flash attention (no-max exp2, R8 TILE + raw v_exp) ----
__global__ __launch_bounds__(256, 4) void msa_attn(
    const u16* __restrict__ qg, const u16* __restrict__ kg,
    const u16* __restrict__ vtg, u16* __restrict__ att)
{
    __shared__ u16 lds_k[2][4096];
    __shared__ u16 lds_v[2][4096];

    const int tid = threadIdx.x, l = tid & 63, w = tid >> 6;
    const int lr = l & 15, lg = l >> 4;

    const int lin = blockIdx.y * 16 + blockIdx.x;
    const int xcd = lin & 7, seq = lin >> 3;
    const int bh  = xcd * 8 + (seq & 7);
    const int q0  = (seq >> 3) * 128;
    const int b = bh >> 4, h = bh & 15;

    const u16* qp  = qg  + (size_t)bh * T_SEQ * HD;
    const u16* kp  = kg  + (size_t)bh * T_SEQ * HD;
    const u16* vtp = vtg + (size_t)bh * HD * T_SEQ;

    const int R0 = w * 16 + (l >> 3), R1 = R0 + 8, c8p = l & 7;
    const int sw0 = (c8p ^ (R0 & 7)) << 3, sw1 = (c8p ^ (R1 & 7)) << 3;
    const size_t koff0 = (size_t)invpi(R0) * HD + sw0;
    const size_t koff1 = (size_t)invpi(R1) * HD + sw1;
    const size_t voff0 = (size_t)R0 * T_SEQ + sw0;
    const size_t voff1 = (size_t)R1 * T_SEQ + sw1;

#define STAGE(bufi, kvb) do {                                                              \
    __builtin_amdgcn_global_load_lds((gptr_t)(kp + (size_t)(kvb) * HD + koff0),            \
                                     (lptr_t)&lds_k[bufi][w * 1024],       16, 0, 0);      \
    __builtin_amdgcn_global_load_lds((gptr_t)(kp + (size_t)(kvb) * HD + koff1),            \
                                     (lptr_t)&lds_k[bufi][w * 1024 + 512], 16, 0, 0);      \
    __builtin_amdgcn_global_load_lds((gptr_t)(vtp + (size_t)(kvb) + voff0),                \
                                     (lptr_t)&lds_v[bufi][w * 1024],       16, 0, 0);      \
    __builtin_amdgcn_global_load_lds((gptr_t)(vtp + (size_t)(kvb) + voff1),                \
                                     (lptr_t)&lds_v[bufi][w * 1024 + 512], 16, 0, 0);      \
} while (0)

    STAGE(0, 0);
    __builtin_amdgcn_sched_barrier(0);

    bf16x8 qf[2][2];
    #pragma unroll
    for (int qt = 0; qt < 2; qt++)
        #pragma unroll
        for (int kk = 0; kk < 2; kk++)
            qf[qt][kk] = *(const bf16x8*)(qp +
                (size_t)(q0 + w * 32 + qt * 16 + lr) * HD + (kk * 4 + lg) * 8);

    f32x4 o[2][4];
    #pragma unroll
    for (int qt = 0; qt < 2; qt++)
        #pragma unroll
        for (int dt = 0; dt < 4; dt++) o[qt][dt] = (f32x4){0.f, 0.f, 0.f, 0.f};
    f32x4 l_acc[2] = {(f32x4){0.f, 0.f, 0.f, 0.f}, (f32x4){0.f, 0.f, 0.f, 0.f}};

    const u32x4 onesw = {0x3f803f80u, 0x3f803f80u, 0x3f803f80u, 0x3f803f80u};
    const bf16x8 onesf = *(const bf16x8*)&onesw;

    f32x4 s0[4], s1[4];

#define COMPUTE_S(bufi) do {                                                               \
    const u16* ksb_ = &lds_k[bufi][0];                                                     \
    __builtin_amdgcn_s_setprio(1);                                                         \
    _Pragma("unroll")                                                                      \
    for (int kk = 0; kk < 2; kk++) {                                                       \
        bf16x8 kf[4];                                                                      \
        _Pragma("unroll")                                                                  \
        for (int m = 0; m < 4; m++)                                                        \
            kf[m] = *(const bf16x8*)&ksb_[m * 1024 + lr * 64 +                             \
                                          ((((kk << 2) | lg) ^ (lr & 7)) << 3)];           \
        if (kk == 0) {                                                                     \
            _Pragma("unroll")                                                              \
            for (int m = 0; m < 4; m++) {                                                  \
                s0[m] = __builtin_amdgcn_mfma_f32_16x16x32_bf16(                           \
                    kf[m], qf[0][0], (f32x4){0.f, 0.f, 0.f, 0.f}, 0, 0, 0);                \
                s1[m] = __builtin_amdgcn_mfma_f32_16x16x32_bf16(                           \
                    kf[m], qf[1][0], (f32x4){0.f, 0.f, 0.f, 0.f}, 0, 0, 0);                \
            }                                                                              \
        } else {                                                                           \
            _Pragma("unroll")                                                              \
            for (int m = 0; m < 4; m++) {                                                  \
                s0[m] = __builtin_amdgcn_mfma_f32_16x16x32_bf16(kf[m], qf[0][1], s0[m], 0, 0, 0); \
                s1[m] = __builtin_amdgcn_mfma_f32_16x16x32_bf16(kf[m], qf[1][1], s1[m], 0, 0, 0); \
            }                                                                              \
        }                                                                                  \
    }                                                                                      \
    __builtin_amdgcn_s_setprio(0);                                                         \
} while (0)

// full tile: S -> exp2 (raw v_exp_f32) -> pack -> PV (V reads inline per-kk)
#define TILE(bufi) do {                                                                    \
    COMPUTE_S(bufi);                                                                       \
    u32 pw[2][2][4];                                                                       \
    _Pragma("unroll")                                                                      \
    for (int qt = 0; qt < 2; qt++) {                                                       \
        f32x4* sq = qt ? s1 : s0;                                                          \
        _Pragma("unroll")                                                                  \
        for (int m = 0; m < 4; m++)                                                        \
            _Pragma("unroll")                                                              \
            for (int i = 0; i < 4; i++) sq[m][i] = fexp2(sq[m][i]);                        \
        _Pragma("unroll")                                                                  \
        for (int kk = 0; kk < 2; kk++)                                                     \
            _Pragma("unroll")                                                              \
            for (int wd = 0; wd < 4; wd++)                                                 \
                pw[qt][kk][wd] = cvtpk(sq[2 * kk + (wd >> 1)][2 * (wd & 1)],               \
                                       sq[2 * kk + (wd >> 1)][2 * (wd & 1) + 1]);          \
    }                                                                                      \
    const u16* vsb_ = &lds_v[bufi][0];                                                     \
    __builtin_amdgcn_s_setprio(1);                                                         \
    _Pragma("unroll")                                                                      \
    for (int kk = 0; kk < 2; kk++) {                                                       \
        u32x4 p0w = {pw[0][kk][0], pw[0][kk][1], pw[0][kk][2], pw[0][kk][3]};              \
        u32x4 p1w = {pw[1][kk][0], pw[1][kk][1], pw[1][kk][2], pw[1][kk][3]};              \
        bf16x8 pf0 = *(bf16x8*)&p0w, pf1 = *(bf16x8*)&p1w;                                 \
        l_acc[0] = __builtin_amdgcn_mfma_f32_16x16x32_bf16(onesf, pf0, l_acc[0], 0, 0, 0); \
        l_acc[1] = __builtin_amdgcn_mfma_f32_16x16x32_bf16(onesf, pf1, l_acc[1], 0, 0, 0); \
        _Pragma("unroll")                                                                  \
        for (int dt = 0; dt < 4; dt++) {                                                   \
            bf16x8 vf = *(const bf16x8*)&vsb_[dt * 1024 + lr * 64 +                        \
                                              ((((kk << 2) | lg) ^ (lr & 7)) << 3)];       \
            o[0][dt] = __builtin_amdgcn_mfma_f32_16x16x32_bf16(vf, pf0, o[0][dt], 0, 0, 0);\
            o[1][dt] = __builtin_amdgcn_mfma_f32_16x16x32_bf16(vf, pf1, o[1][dt], 0, 0, 0);\
        }                                                                                  \
    }                                                                                      \
    __builtin_amdgcn_s_setprio(0);                                                         \
} while (0)

    for (int tt = 0; tt < NT; tt += 2) {
        // ---- tile tt in buf 0 ----
        __builtin_amdgcn_s_barrier();
        {
            STAGE(1, (tt + 1) * 64);           // tt+1 < NT always (NT even)
            __builtin_amdgcn_sched_barrier(0);
            asm volatile("s_waitcnt vmcnt(4)" ::: "memory");
        }
        __builtin_amdgcn_sched_barrier(0);
        __builtin_amdgcn_s_barrier();
        __builtin_amdgcn_sched_barrier(0);
        TILE(0);

        // ---- tile tt+1 in buf 1 ----
        __builtin_amdgcn_s_barrier();
        if (tt + 2 < NT) {
            STAGE(0, (tt + 2) * 64);
            __builtin_amdgcn_sched_barrier(0);
            asm volatile("s_waitcnt vmcnt(4)" ::: "memory");
        } else {
            asm volatile("s_waitcnt vmcnt(0)" ::: "memory");
        }
        __builtin_amdgcn_sched_barrier(0);
        __builtin_amdgcn_s_barrier();
        __builtin_amdgcn_sched_barrier(0);
        TILE(1);
    }
#undef STAGE
#undef COMPUTE_S
#undef TILE

    // epilogue: O^T[d][q] -> att[t][d] via per-wave LDS transpose
    __syncthreads();
    u16* ep = &lds_k[0][0] + w * 2048;
    #pragma unroll
    for (int qt = 0; qt < 2; qt++) {
        const float iv = 1.0f / l_acc[qt][0];
        #pragma unroll
        for (int dt = 0; dt < 4; dt++) {
            u32 a  = cvtpk(o[qt][dt][0] * iv, o[qt][dt][1] * iv);
            u32 bb = cvtpk(o[qt][dt][2] * iv, o[qt][dt][3] * iv);
            const int row = qt * 16 + lr;
            const int c8 = dt * 2 + (lg >> 1);
            u32* dst = (u32*)&ep[row * 64 + ((c8 ^ (row & 7)) << 3) + (lg & 1) * 4];
            dst[0] = a; dst[1] = bb;
        }
    }
    __syncthreads();
    {
        const int row = l >> 1;
        const int tq = q0 + w * 32 + row;
        u16* gdst = att + ((size_t)b * T_SEQ + tq) * EMB + h * HD;
        #pragma unroll
        for (int ci = 0; ci < 4; ci++) {
            const int c = (l & 1) * 4 + ci;
            u16x8 v = *(const u16x8*)&ep[row * 64 + ((c ^ (row & 7)) << 3)];
            *(u16x8*)&gdst[c * 8] = v;
        }
    }
}

// ---------------- kernel 3: output projection (counted vmcnt, XCD-local tiles) -----
__global__ __launch_bounds__(256) void msa_proj(
    const u16* __restrict__ a, const u16* __restrict__ wb,
    const float* __restrict__ bias, float* __restrict__ y)
{
    __shared__ u16 as[2][8192];
    __shared__ u16 bs[2][8192];

    const int tid = threadIdx.x, l = tid & 63, w = tid >> 6;

    // XCD-local mapping: XCD k owns m-tiles [8k,8k+8), n fastest.
    const int lin = blockIdx.y * 8 + blockIdx.x;   // 0..511
    const int xcd = lin & 7, s = lin >> 3;         // s 0..63
    const int m0 = (xcd * 8 + (s >> 3)) * 128;
    const int n0 = (s & 7) * 128;

    const int wr = (w >> 1) * 64, wc = (w & 1) * 64;
    const int lr = l & 15, lg = l >> 4;

    const int sr = l >> 3, c8 = l & 7;
    size_t aoff[4], boff[4];
    #pragma unroll
    for (int j = 0; j < 4; j++) {
        const int row = w * 32 + j * 8 + sr;
        const int col = (c8 ^ (row & 7)) << 3;
        aoff[j] = (size_t)(m0 + row) * EMB + col;
        boff[j] = (size_t)(n0 + row) * EMB + col;
    }

#define PSTAGE(bi, kk0) do {                                                               \
    _Pragma("unroll")                                                                      \
    for (int j = 0; j < 4; j++) {                                                          \
        __builtin_amdgcn_global_load_lds((gptr_t)(a + aoff[j] + (kk0)),                    \
            (lptr_t)&as[bi][(w * 32 + j * 8) * 64], 16, 0, 0);                             \
        __builtin_amdgcn_global_load_lds((gptr_t)(wb + boff[j] + (kk0)),                   \
            (lptr_t)&bs[bi][(w * 32 + j * 8) * 64], 16, 0, 0);                             \
    }                                                                                      \
} while (0)

#define PCOMPUTE(bi) do {                                                                  \
    bf16x8 af[4][2], bf[4][2];                                                             \
    _Pragma("unroll")                                                                      \
    for (int mt = 0; mt < 4; mt++)                                                         \
        _Pragma("unroll")                                                                  \
        for (int kk = 0; kk < 2; kk++) {                                                   \
            const int row = wr + mt * 16 + lr;                                             \
            const int cc = kk * 4 + lg;                                                    \
            af[mt][kk] = *(const bf16x8*)&as[bi][row * 64 + ((cc ^ (row & 7)) << 3)];      \
        }                                                                                  \
    _Pragma("unroll")                                                                      \
    for (int nt = 0; nt < 4; nt++)                                                         \
        _Pragma("unroll")                                                                  \
        for (int kk = 0; kk < 2; kk++) {                                                   \
            const int row = wc + nt * 16 + lr;                                             \
            const int cc = kk * 4 + lg;                                                    \
            bf[nt][kk] = *(const bf16x8*)&bs[bi][row * 64 + ((cc ^ (row & 7)) << 3)];      \
        }                                                                                  \
    __builtin_amdgcn_s_setprio(1);                                                         \
    _Pragma("unroll")                                                                      \
    for (int mt = 0; mt < 4; mt++)                                                         \
        _Pragma("unroll")                                                                  \
        for (int nt = 0; nt < 4; nt++)                                                     \
            _Pragma("unroll")                                                              \
            for (int kk = 0; kk < 2; kk++)                                                 \
                acc[mt][nt] = __builtin_amdgcn_mfma_f32_16x16x32_bf16(                     \
                    af[mt][kk], bf[nt][kk], acc[mt][nt], 0, 0, 0);                         \
    __builtin_amdgcn_s_setprio(0);                                                         \
} while (0)

    f32x4 acc[4][4];
    #pragma unroll
    for (int mt = 0; mt < 4; mt++)
        #pragma unroll
        for (int nt = 0; nt < 4; nt++) acc[mt][nt] = (f32x4){0.f, 0.f, 0.f, 0.f};

    PSTAGE(0, 0);

    for (int k0 = 0; k0 < EMB; k0 += 128) {
        // ---- K-step k0 in buf 0 ----
        __builtin_amdgcn_s_barrier();
        {
            PSTAGE(1, k0 + 64);
            __builtin_amdgcn_sched_barrier(0);
            asm volatile("s_waitcnt vmcnt(8)" ::: "memory");
        }
        __builtin_amdgcn_sched_barrier(0);
        __builtin_amdgcn_s_barrier();
        __builtin_amdgcn_sched_barrier(0);
        PCOMPUTE(0);

        // ---- K-step k0+64 in buf 1 ----
        __builtin_amdgcn_s_barrier();
        if (k0 + 128 < EMB) {
            PSTAGE(0, k0 + 128);
            __builtin_amdgcn_sched_barrier(0);
            asm volatile("s_waitcnt vmcnt(8)" ::: "memory");
        } else {
            asm volatile("s_waitcnt vmcnt(0)" ::: "memory");
        }
        __builtin_amdgcn_sched_barrier(0);
        __builtin_amdgcn_s_barrier();
        __builtin_amdgcn_sched_barrier(0);
        PCOMPUTE(1);
    }
#undef PSTAGE
#undef PCOMPUTE

    float bv[4];
    #pragma unroll
    for (int nt = 0; nt < 4; nt++) bv[nt] = bias[n0 + wc + nt * 16 + lr];
    #pragma unroll
    for (int mt = 0; mt < 4; mt++)
        #pragma unroll
        for (int nt = 0; nt < 4; nt++)
            #pragma unroll
            for (int i = 0; i < 4; i++) {
                const size_t row = (size_t)(m0 + wr + mt * 16 + lg * 4 + i);
                const int col = n0 + wc + nt * 16 + lr;
                y[row * EMB + col] = acc[mt][nt][i] + bv[nt];
            }
}

extern "C" void kernel_launch(void* const* d_in, const int* in_sizes, int n_in,
                              void* d_out, int out_size, void* d_ws, size_t ws_size,
                              hipStream_t stream)
{
    const float* x     = (const float*)d_in[0];
    const float* wqkv  = (const float*)d_in[1];
    const float* bqkv  = (const float*)d_in[2];
    const float* wproj = (const float*)d_in[3];
    const float* bproj = (const float*)d_in[4];
    float* y = (float*)d_out;

    char* ws = (char*)d_ws;
    u16* q    = (u16*)(ws);
    u16* k    = (u16*)(ws + ((size_t)16 << 20));
    u16* vt   = (u16*)(ws + ((size_t)32 << 20));
    u16* att  = (u16*)(ws + ((size_t)48 << 20));
    u16* wb   = (u16*)(ws + ((size_t)64 << 20));
    u16* wimg = (u16*)(ws + ((size_t)66 << 20));

    msa_convert<<<1030, 256, 0, stream>>>(wproj, wqkv, wb, wimg);
    msa_qkv<<<dim3(T_SEQ / 64, BATCH * NH), 256, 0, stream>>>(x, wimg, bqkv, q, k, vt);
    msa_attn<<<dim3(16, 64), 256, 0, stream>>>(q, k, vt, att);
    msa_proj<<<dim3(8, 64), 256, 0, stream>>>(att, wb, bproj, y);
}

// Round 11
// 113.594 us; speedup vs baseline: 1.3124x; 1.0072x over previous
//
#include <hip/hip_runtime.h>
#include <hip/hip_bf16.h>
#include <cstdint>
#include <cstddef>

#define T_SEQ 2048
#define NH    16
#define HD    64
#define EMB   1024
#define BATCH 4
#define NT    (T_SEQ / 64)

typedef unsigned short u16;
typedef unsigned int   u32;
typedef u16   u16x8  __attribute__((ext_vector_type(8)));
typedef short bf16x8 __attribute__((ext_vector_type(8)));
typedef float f32x4  __attribute__((ext_vector_type(4)));
typedef u32   u32x4  __attribute__((ext_vector_type(4)));

typedef const __attribute__((address_space(1))) void* gptr_t;
typedef __attribute__((address_space(3))) void*       lptr_t;

__device__ __forceinline__ u16 f2bf(float f) {
    union { float f; unsigned u; } v; v.f = f;
    unsigned r = v.u + 0x7fffu + ((v.u >> 16) & 1u);
    return (u16)(r >> 16);
}

__device__ __forceinline__ u32 cvtpk(float lo, float hi) {
    u32 r;
    asm("v_cvt_pk_bf16_f32 %0, %1, %2" : "=v"(r) : "v"(lo), "v"(hi));
    return r;
}

// raw v_exp_f32: 2^x, no OCML subnormal fixup (args bounded; FTZ result is
// exactly what softmax wants for very negative x).
__device__ __forceinline__ float fexp2(float x) {
    float r;
    asm("v_exp_f32 %0, %1" : "=v"(r) : "v"(x));
    return r;
}

// storage row R -> source kv row, so that S^T C-layout == PV fragment layout.
__device__ __forceinline__ int invpi(int R) {
    return ((R >> 5) << 5) | (((R >> 2) & 3) << 3) | (((R >> 4) & 1) << 2) | (R & 3);
}

// ---------------- kernel 0: fused weight converts ----------------
__global__ __launch_bounds__(256) void msa_convert(
    const float* __restrict__ wproj, const float* __restrict__ wqkv,
    u16* __restrict__ wb, u16* __restrict__ wimg)
{
    const int bid = blockIdx.x, tid = threadIdx.x;
    if (bid < 1024) {
        int i = (bid * 256 + tid) * 4;
        f32x4 f = *(const f32x4*)(wproj + i);
        u16 o0 = f2bf(f[0]), o1 = f2bf(f[1]), o2 = f2bf(f[2]), o3 = f2bf(f[3]);
        wb[i + 0] = o0; wb[i + 1] = o1; wb[i + 2] = o2; wb[i + 3] = o3;
    } else {
        const int gid = (bid - 1024) * 256 + tid;   // 0..1535
        if (gid < 1536) {
            const int r = gid >> 3, c8 = gid & 7;
            const float* src = wqkv + r * 64 + c8 * 8;
            f32x4 f0 = *(const f32x4*)src, f1 = *(const f32x4*)(src + 4);
            u32x4 pk = { cvtpk(f0[0], f0[1]), cvtpk(f0[2], f0[3]),
                         cvtpk(f1[0], f1[1]), cvtpk(f1[2], f1[3]) };
            *(u32x4*)&wimg[r * 64 + ((c8 ^ (r & 7)) << 3)] = pk;
        }
    }
}

// ---------------- kernel 1: QKV projection (bf16 MFMA) ----------------
__global__ __launch_bounds__(256) void msa_qkv(
    const float* __restrict__ x, const u16* __restrict__ wimg,
    const float* __restrict__ bqkv,
    u16* __restrict__ qg, u16* __restrict__ kg, u16* __restrict__ vt)
{
    __shared__ __align__(16) u16 sm[16384];   // 32 KB
    u16* Xs = sm;                              // [64][64] swizzled
    u16* Wl = sm + 4096;                       // [192][64] swizzled image

    const int tid = threadIdx.x, l = tid & 63, w = tid >> 6;
    const int lr = l & 15, lg = l >> 4;
    const int bh = blockIdx.y, b = bh >> 4, h = bh & 15;
    const int t0 = blockIdx.x * 64;

    #pragma unroll
    for (int j = 0; j < 6; j++)
        __builtin_amdgcn_global_load_lds((gptr_t)(wimg + j * 2048 + w * 512 + l * 8),
                                         (lptr_t)(Wl + j * 2048 + w * 512), 16, 0, 0);

    #pragma unroll
    for (int g = 0; g < 2; g++) {
        const int chunk = g * 256 + tid;
        const int row = chunk >> 3, c8 = chunk & 7;
        const float* src = x + ((size_t)(b * T_SEQ + t0 + row)) * EMB + h * HD + c8 * 8;
        f32x4 f0 = *(const f32x4*)src, f1 = *(const f32x4*)(src + 4);
        u32x4 pk = { cvtpk(f0[0], f0[1]), cvtpk(f0[2], f0[3]),
                     cvtpk(f1[0], f1[1]), cvtpk(f1[2], f1[3]) };
        *(u32x4*)&Xs[row * 64 + ((c8 ^ (row & 7)) << 3)] = pk;
    }

    float bv[12];
    #pragma unroll
    for (int dt = 0; dt < 12; dt++) bv[dt] = bqkv[dt * 16 + lr];

    __syncthreads();

    const int xr = w * 16 + lr;
    bf16x8 af[2];
    #pragma unroll
    for (int kk = 0; kk < 2; kk++)
        af[kk] = *(const bf16x8*)&Xs[xr * 64 + ((((kk << 2) | lg) ^ (xr & 7)) << 3)];

    f32x4 acc[12];
    #pragma unroll
    for (int dt = 0; dt < 12; dt++) acc[dt] = (f32x4){0.f, 0.f, 0.f, 0.f};
    #pragma unroll
    for (int dt = 0; dt < 12; dt++) {
        const int wr = dt * 16 + lr;
        #pragma unroll
        for (int kk = 0; kk < 2; kk++) {
            bf16x8 wf = *(const bf16x8*)&Wl[wr * 64 + ((((kk << 2) | lg) ^ (wr & 7)) << 3)];
            acc[dt] = __builtin_amdgcn_mfma_f32_16x16x32_bf16(af[kk], wf, acc[dt], 0, 0, 0);
        }
    }

    const float qscale = 0.125f * 1.44269504088896340736f;
    #pragma unroll
    for (int dt = 0; dt < 12; dt++)
        #pragma unroll
        for (int i = 0; i < 4; i++) {
            acc[dt][i] += bv[dt];
            if (dt < 4) acc[dt][i] *= qscale;
        }

    // V: direct 8B stores
    #pragma unroll
    for (int dt = 8; dt < 12; dt++) {
        const int d = (dt - 8) * 16 + lr;
        const int t = t0 + w * 16 + lg * 4;
        u32 w0 = cvtpk(acc[dt][0], acc[dt][1]);
        u32 w1 = cvtpk(acc[dt][2], acc[dt][3]);
        u32* dst = (u32*)&vt[((size_t)bh * HD + d) * T_SEQ + t];
        dst[0] = w0; dst[1] = w1;
    }

    // Q,K via per-wave LDS transpose then coalesced stores
    __syncthreads();
    u16* qep = sm + w * 1024;
    u16* kep = sm + 4096 + w * 1024;
    #pragma unroll
    for (int dt = 0; dt < 8; dt++) {
        u16* ep = dt < 4 ? qep : kep;
        const int d = (dt & 3) * 16 + lr;
        const int c8 = d >> 3;
        #pragma unroll
        for (int i = 0; i < 4; i++) {
            const int r = lg * 4 + i;
            ep[r * 64 + ((c8 ^ (r & 7)) << 3) + (d & 7)] = (u16)cvtpk(acc[dt][i], acc[dt][i]);
        }
    }
    __syncthreads();
    #pragma unroll
    for (int j = 0; j < 2; j++) {
        const int row = l >> 2, c8 = (l & 3) * 2 + j;
        const size_t grow = ((size_t)bh * T_SEQ + t0 + w * 16 + row) * HD + c8 * 8;
        u16x8 vq = *(const u16x8*)&qep[row * 64 + ((c8 ^ (row & 7)) << 3)];
        *(u16x8*)&qg[grow] = vq;
        u16x8 vk = *(const u16x8*)&kep[row * 64 + ((c8 ^ (row & 7)) << 3)];
        *(u16x8*)&kg[grow] = vk;
    }
}

// ---------------- kernel 2: flash attention (no-max exp2, R8 TILE + raw v_exp) ----
__global__ __launch_bounds__(256, 4) void msa_attn(
    const u16* __restrict__ qg, const u16* __restrict__ kg,
    const u16* __restrict__ vtg, u16* __restrict__ att)
{
    __shared__ u16 lds_k[2][4096];
    __shared__ u16 lds_v[2][4096];

    const int tid = threadIdx.x, l = tid & 63, w = tid >> 6;
    const int lr = l & 15, lg = l >> 4;

    const int lin = blockIdx.y * 16 + blockIdx.x;
    const int xcd = lin & 7, seq = lin >> 3;
    const int bh  = xcd * 8 + (seq & 7);
    const int q0  = (seq >> 3) * 128;
    const int b = bh >> 4, h = bh & 15;

    const u16* qp  = qg  + (size_t)bh * T_SEQ * HD;
    const u16* kp  = kg  + (size_t)bh * T_SEQ * HD;
    const u16* vtp = vtg + (size_t)bh * HD * T_SEQ;

    const int R0 = w * 16 + (l >> 3), R1 = R0 + 8, c8p = l & 7;
    const int sw0 = (c8p ^ (R0 & 7)) << 3, sw1 = (c8p ^ (R1 & 7)) << 3;
    const size_t koff0 = (size_t)invpi(R0) * HD + sw0;
    const size_t koff1 = (size_t)invpi(R1) * HD + sw1;
    const size_t voff0 = (size_t)R0 * T_SEQ + sw0;
    const size_t voff1 = (size_t)R1 * T_SEQ + sw1;

#define STAGE(bufi, kvb) do {                                                              \
    __builtin_amdgcn_global_load_lds((gptr_t)(kp + (size_t)(kvb) * HD + koff0),            \
                                     (lptr_t)&lds_k[bufi][w * 1024],       16, 0, 0);      \
    __builtin_amdgcn_global_load_lds((gptr_t)(kp + (size_t)(kvb) * HD + koff1),            \
                                     (lptr_t)&lds_k[bufi][w * 1024 + 512], 16, 0, 0);      \
    __builtin_amdgcn_global_load_lds((gptr_t)(vtp + (size_t)(kvb) + voff0),                \
                                     (lptr_t)&lds_v[bufi][w * 1024],       16, 0, 0);      \
    __builtin_amdgcn_global_load_lds((gptr_t)(vtp + (size_t)(kvb) + voff1),                \
                                     (lptr_t)&lds_v[bufi][w * 1024 + 512], 16, 0, 0);      \
} while (0)

    STAGE(0, 0);
    __builtin_amdgcn_sched_barrier(0);

    bf16x8 qf[2][2];
    #pragma unroll
    for (int qt = 0; qt < 2; qt++)
        #pragma unroll
        for (int kk = 0; kk < 2; kk++)
            qf[qt][kk] = *(const bf16x8*)(qp +
                (size_t)(q0 + w * 32 + qt * 16 + lr) * HD + (kk * 4 + lg) * 8);

    f32x4 o[2][4];
    #pragma unroll
    for (int qt = 0; qt < 2; qt++)
        #pragma unroll
        for (int dt = 0; dt < 4; dt++) o[qt][dt] = (f32x4){0.f, 0.f, 0.f, 0.f};
    f32x4 l_acc[2] = {(f32x4){0.f, 0.f, 0.f, 0.f}, (f32x4){0.f, 0.f, 0.f, 0.f}};

    const u32x4 onesw = {0x3f803f80u, 0x3f803f80u, 0x3f803f80u, 0x3f803f80u};
    const bf16x8 onesf = *(const bf16x8*)&onesw;

    f32x4 s0[4], s1[4];

#define COMPUTE_S(bufi) do {                                                               \
    const u16* ksb_ = &lds_k[bufi][0];                                                     \
    __builtin_amdgcn_s_setprio(1);                                                         \
    _Pragma("unroll")                                                                      \
    for (int kk = 0; kk < 2; kk++) {                                                       \
        bf16x8 kf[4];                                                                      \
        _Pragma("unroll")                                                                  \
        for (int m = 0; m < 4; m++)                                                        \
            kf[m] = *(const bf16x8*)&ksb_[m * 1024 + lr * 64 +                             \
                                          ((((kk << 2) | lg) ^ (lr & 7)) << 3)];           \
        if (kk == 0) {                                                                     \
            _Pragma("unroll")                                                              \
            for (int m = 0; m < 4; m++) {                                                  \
                s0[m] = __builtin_amdgcn_mfma_f32_16x16x32_bf16(                           \
                    kf[m], qf[0][0], (f32x4){0.f, 0.f, 0.f, 0.f}, 0, 0, 0);                \
                s1[m] = __builtin_amdgcn_mfma_f32_16x16x32_bf16(                           \
                    kf[m], qf[1][0], (f32x4){0.f, 0.f, 0.f, 0.f}, 0, 0, 0);                \
            }                                                                              \
        } else {                                                                           \
            _Pragma("unroll")                                                              \
            for (int m = 0; m < 4; m++) {                                                  \
                s0[m] = __builtin_amdgcn_mfma_f32_16x16x32_bf16(kf[m], qf[0][1], s0[m], 0, 0, 0); \
                s1[m] = __builtin_amdgcn_mfma_f32_16x16x32_bf16(kf[m], qf[1][1], s1[m], 0, 0, 0); \
            }                                                                              \
        }                                                                                  \
    }                                                                                      \
    __builtin_amdgcn_s_setprio(0);                                                         \
} while (0)

// full tile: S -> exp2 (raw v_exp_f32) -> pack -> PV (V reads inline per-kk)
#define TILE(bufi) do {                                                                    \
    COMPUTE_S(bufi);                                                                       \
    u32 pw[2][2][4];                                                                       \
    _Pragma("unroll")                                                                      \
    for (int qt = 0; qt < 2; qt++) {                                                       \
        f32x4* sq = qt ? s1 : s0;                                                          \
        _Pragma("unroll")                                                                  \
        for (int m = 0; m < 4; m++)                                                        \
            _Pragma("unroll")                                                              \
            for (int i = 0; i < 4; i++) sq[m][i] = fexp2(sq[m][i]);                        \
        _Pragma("unroll")                                                                  \
        for (int kk = 0; kk < 2; kk++)                                                     \
            _Pragma("unroll")                                                              \
            for (int wd = 0; wd < 4; wd++)                                                 \
                pw[qt][kk][wd] = cvtpk(sq[2 * kk + (wd >> 1)][2 * (wd & 1)],               \
                                       sq[2 * kk + (wd >> 1)][2 * (wd & 1) + 1]);          \
    }                                                                                      \
    const u16* vsb_ = &lds_v[bufi][0];                                                     \
    __builtin_amdgcn_s_setprio(1);                                                         \
    _Pragma("unroll")                                                                      \
    for (int kk = 0; kk < 2; kk++) {                                                       \
        u32x4 p0w = {pw[0][kk][0], pw[0][kk][1], pw[0][kk][2], pw[0][kk][3]};              \
        u32x4 p1w = {pw[1][kk][0], pw[1][kk][1], pw[1][kk][2], pw[1][kk][3]};              \
        bf16x8 pf0 = *(bf16x8*)&p0w, pf1 = *(bf16x8*)&p1w;                                 \
        l_acc[0] = __builtin_amdgcn_mfma_f32_16x16x32_bf16(onesf, pf0, l_acc[0], 0, 0, 0); \
        l_acc[1] = __builtin_amdgcn_mfma_f32_16x16x32_bf16(onesf, pf1, l_acc[1], 0, 0, 0); \
        _Pragma("unroll")                                                                  \
        for (int dt = 0; dt < 4; dt++) {                                                   \
            bf16x8 vf = *(const bf16x8*)&vsb_[dt * 1024 + lr * 64 +                        \
                                              ((((kk << 2) | lg) ^ (lr & 7)) << 3)];       \
            o[0][dt] = __builtin_amdgcn_mfma_f32_16x16x32_bf16(vf, pf0, o[0][dt], 0, 0, 0);\
            o[1][dt] = __builtin_amdgcn_mfma_f32_16x16x32_bf16(vf, pf1, o[1][dt], 0, 0, 0);\
        }                                                                                  \
    }                                                                                      \
    __builtin_amdgcn_s_setprio(0);                                                         \
} while (0)

    for (int tt = 0; tt < NT; tt += 2) {
        // ---- tile tt in buf 0 ----
        __builtin_amdgcn_s_barrier();
        {
            STAGE(1, (tt + 1) * 64);           // tt+1 < NT always (NT even)
            __builtin_amdgcn_sched_barrier(0);
            asm volatile("s_waitcnt vmcnt(4)" ::: "memory");
        }
        __builtin_amdgcn_sched_barrier(0);
        __builtin_amdgcn_s_barrier();
        __builtin_amdgcn_sched_barrier(0);
        TILE(0);

        // ---- tile tt+1 in buf 1 ----
        __builtin_amdgcn_s_barrier();
        if (tt + 2 < NT) {
            STAGE(0, (tt + 2) * 64);
            __builtin_amdgcn_sched_barrier(0);
            asm volatile("s_waitcnt vmcnt(4)" ::: "memory");
        } else {
            asm volatile("s_waitcnt vmcnt(0)" ::: "memory");
        }
        __builtin_amdgcn_sched_barrier(0);
        __builtin_amdgcn_s_barrier();
        __builtin_amdgcn_sched_barrier(0);
        TILE(1);
    }
#undef STAGE
#undef COMPUTE_S
#undef TILE

    // epilogue: O^T[d][q] -> att[t][d] via per-wave LDS transpose
    __syncthreads();
    u16* ep = &lds_k[0][0] + w * 2048;
    #pragma unroll
    for (int qt = 0; qt < 2; qt++) {
        const float iv = 1.0f / l_acc[qt][0];
        #pragma unroll
        for (int dt = 0; dt < 4; dt++) {
            u32 a  = cvtpk(o[qt][dt][0] * iv, o[qt][dt][1] * iv);
            u32 bb = cvtpk(o[qt][dt][2] * iv, o[qt][dt][3] * iv);
            const int row = qt * 16 + lr;
            const int c8 = dt * 2 + (lg >> 1);
            u32* dst = (u32*)&ep[row * 64 + ((c8 ^ (row & 7)) << 3) + (lg & 1) * 4];
            dst[0] = a; dst[1] = bb;
        }
    }
    __syncthreads();
    {
        const int row = l >> 1;
        const int tq = q0 + w * 32 + row;
        u16* gdst = att + ((size_t)b * T_SEQ + tq) * EMB + h * HD;
        #pragma unroll
        for (int ci = 0; ci < 4; ci++) {
            const int c = (l & 1) * 4 + ci;
            u16x8 v = *(const u16x8*)&ep[row * 64 + ((c ^ (row & 7)) << 3)];
            *(u16x8*)&gdst[c * 8] = v;
        }
    }
}

// ---------------- kernel 3: output projection (8-wave, counted vmcnt, XCD-local) ----
__global__ __launch_bounds__(512) void msa_proj(
    const u16* __restrict__ a, const u16* __restrict__ wb,
    const float* __restrict__ bias, float* __restrict__ y)
{
    __shared__ u16 as[2][8192];
    __shared__ u16 bs[2][8192];

    const int tid = threadIdx.x, l = tid & 63, w = tid >> 6;   // w 0..7

    // XCD-local mapping: XCD k owns m-tiles [8k,8k+8), n fastest.
    const int lin = blockIdx.y * 8 + blockIdx.x;   // 0..511
    const int xcd = lin & 7, s = lin >> 3;         // s 0..63
    const int m0 = (xcd * 8 + (s >> 3)) * 128;
    const int n0 = (s & 7) * 128;

    // wave grid 4m x 2n: each wave owns 32(m) x 64(n)
    const int wr = (w >> 1) * 32, wc = (w & 1) * 64;
    const int lr = l & 15, lg = l >> 4;

    const int sr = l >> 3, c8 = l & 7;
    size_t aoff[2], boff[2];
    #pragma unroll
    for (int j = 0; j < 2; j++) {
        const int row = w * 16 + j * 8 + sr;       // 0..127
        const int col = (c8 ^ (row & 7)) << 3;
        aoff[j] = (size_t)(m0 + row) * EMB + col;
        boff[j] = (size_t)(n0 + row) * EMB + col;
    }

#define PSTAGE(bi, kk0) do {                                                               \
    _Pragma("unroll")                                                                      \
    for (int j = 0; j < 2; j++) {                                                          \
        __builtin_amdgcn_global_load_lds((gptr_t)(a + aoff[j] + (kk0)),                    \
            (lptr_t)&as[bi][(w * 16 + j * 8) * 64], 16, 0, 0);                             \
        __builtin_amdgcn_global_load_lds((gptr_t)(wb + boff[j] + (kk0)),                   \
            (lptr_t)&bs[bi][(w * 16 + j * 8) * 64], 16, 0, 0);                             \
    }                                                                                      \
} while (0)

#define PCOMPUTE(bi) do {                                                                  \
    bf16x8 af[2][2], bf[4][2];                                                             \
    _Pragma("unroll")                                                                      \
    for (int mt = 0; mt < 2; mt++)                                                         \
        _Pragma("unroll")                                                                  \
        for (int kk = 0; kk < 2; kk++) {                                                   \
            const int row = wr + mt * 16 + lr;                                             \
            const int cc = kk * 4 + lg;                                                    \
            af[mt][kk] = *(const bf16x8*)&as[bi][row * 64 + ((cc ^ (row & 7)) << 3)];      \
        }                                                                                  \
    _Pragma("unroll")                                                                      \
    for (int nt = 0; nt < 4; nt++)                                                         \
        _Pragma("unroll")                                                                  \
        for (int kk = 0; kk < 2; kk++) {                                                   \
            const int row = wc + nt * 16 + lr;                                             \
            const int cc = kk * 4 + lg;                                                    \
            bf[nt][kk] = *(const bf16x8*)&bs[bi][row * 64 + ((cc ^ (row & 7)) << 3)];      \
        }                                                                                  \
    __builtin_amdgcn_s_setprio(1);                                                         \
    _Pragma("unroll")                                                                      \
    for (int mt = 0; mt < 2; mt++)                                                         \
        _Pragma("unroll")                                                                  \
        for (int nt = 0; nt < 4; nt++)                                                     \
            _Pragma("unroll")                                                              \
            for (int kk = 0; kk < 2; kk++)                                                 \
                acc[mt][nt] = __builtin_amdgcn_mfma_f32_16x16x32_bf16(                     \
                    af[mt][kk], bf[nt][kk], acc[mt][nt], 0, 0, 0);                         \
    __builtin_amdgcn_s_setprio(0);                                                         \
} while (0)

    f32x4 acc[2][4];
    #pragma unroll
    for (int mt = 0; mt < 2; mt++)
        #pragma unroll
        for (int nt = 0; nt < 4; nt++) acc[mt][nt] = (f32x4){0.f, 0.f, 0.f, 0.f};

    PSTAGE(0, 0);

    for (int k0 = 0; k0 < EMB; k0 += 128) {
        // ---- K-step k0 in buf 0 ----
        __builtin_amdgcn_s_barrier();
        {
            PSTAGE(1, k0 + 64);
            __builtin_amdgcn_sched_barrier(0);
            asm volatile("s_waitcnt vmcnt(4)" ::: "memory");
        }
        __builtin_amdgcn_sched_barrier(0);
        __builtin_amdgcn_s_barrier();
        __builtin_amdgcn_sched_barrier(0);
        PCOMPUTE(0);

        // ---- K-step k0+64 in buf 1 ----
        __builtin_amdgcn_s_barrier();
        if (k0 + 128 < EMB) {
            PSTAGE(0, k0 + 128);
            __builtin_amdgcn_sched_barrier(0);
            asm volatile("s_waitcnt vmcnt(4)" ::: "memory");
        } else {
            asm volatile("s_waitcnt vmcnt(0)" ::: "memory");
        }
        __builtin_amdgcn_sched_barrier(0);
        __builtin_amdgcn_s_barrier();
        __builtin_amdgcn_sched_barrier(0);
        PCOMPUTE(1);
    }
#undef PSTAGE
#undef PCOMPUTE

    float bv[4];
    #pragma unroll
    for (int nt = 0; nt < 4; nt++) bv[nt] = bias[n0 + wc + nt * 16 + lr];
    #pragma unroll
    for (int mt = 0; mt < 2; mt++)
        #pragma unroll
        for (int nt = 0; nt < 4; nt++)
            #pragma unroll
            for (int i = 0; i < 4; i++) {
                const size_t row = (size_t)(m0 + wr + mt * 16 + lg * 4 + i);
                const int col = n0 + wc + nt * 16 + lr;
                y[row * EMB + col] = acc[mt][nt][i] + bv[nt];
            }
}

extern "C" void kernel_launch(void* const* d_in, const int* in_sizes, int n_in,
                              void* d_out, int out_size, void* d_ws, size_t ws_size,
                              hipStream_t stream)
{
    const float* x     = (const float*)d_in[0];
    const float* wqkv  = (const float*)d_in[1];
    const float* bqkv  = (const float*)d_in[2];
    const float* wproj = (const float*)d_in[3];
    const float* bproj = (const float*)d_in[4];
    float* y = (float*)d_out;

    char* ws = (char*)d_ws;
    u16* q    = (u16*)(ws);
    u16* k    = (u16*)(ws + ((size_t)16 << 20));
    u16* vt   = (u16*)(ws + ((size_t)32 << 20));
    u16* att  = (u16*)(ws + ((size_t)48 << 20));
    u16* wb   = (u16*)(ws + ((size_t)64 << 20));
    u16* wimg = (u16*)(ws + ((size_t)66 << 20));

    msa_convert<<<1030, 256, 0, stream>>>(wproj, wqkv, wb, wimg);
    msa_qkv<<<dim3(T_SEQ / 64, BATCH * NH), 256, 0, stream>>>(x, wimg, bqkv, q, k, vt);
    msa_attn<<<dim3(16, 64), 256, 0, stream>>>(q, k, vt, att);
    msa_proj<<<dim3(8, 64), 512, 0, stream>>>(att, wb, bproj, y);
}